// Round 15
// baseline (217.623 us; speedup 1.0000x reference)
//
#include <hip/hip_runtime.h>

typedef __attribute__((ext_vector_type(8))) short short8;
typedef __attribute__((ext_vector_type(4))) short short4v;
typedef __attribute__((ext_vector_type(4))) float float4v;

#define MFMA16(a, b, c) __builtin_amdgcn_mfma_f32_16x16x32_bf16((a), (b), (c), 0, 0, 0)

constexpr int kThreads = 512;  // 8 waves; 72 KiB LDS -> 2 blocks/CU -> 4 waves/SIMD
// GRID: 512 blocks. Block bp handles batch b = bp>>1, q-tile half h = bp&1.
// K/V processed in TWO position-halves of 256; online softmax carries
// o/m/sum across them.
//
// LDS (ushort units), 36864 us = 73728 B (= 72 KiB; 2 x 72 = 144 KiB < 160
// KiB pool with 16 KiB slack — r14's exact-fit 2 x 80 KiB did NOT co-reside:
// occupancy stayed 22%, so leave headroom for any per-WG reservation):
//   [0,     16384)  Ksw : K pos-half (256 rows). Per row 8 granules of 8 us:
//                   granule g = cp*4+quad XOR (lrow&7); content
//                   [K[pos][cp*32+quad*4+0..3], K[pos][cp*32+16+quad*4+0..3]]
//   [16384, 32768)  Vsw : V pos-half, d-major 256 us/channel:
//                   (d<<8) + (qg2<<6) + (gv<<3) + jj, gv = kpqL^(d&7)^qg2
//   [32768, 36864)  slot : ONE 64x64 W matrix, staged just-in-time
//                   (Wq -> Q, Wk -> K, Wv -> V, restage for half 1, Wd last)
constexpr int LDS_TOTAL_BYTES = 73728;
// REGISTER REALITY (r10-r13): 1024-thread blocks get a 64-VGPR budget and
// spill. 512-thread blocks with __launch_bounds__(512,2) allocate 128 VGPR
// clean (six builds). Occupancy must come from 2 blocks/CU.

static __device__ __forceinline__ unsigned short f2bf(float f) {
  // native cast -> HW v_cvt_pk_bf16_f32 (RNE)
  __bf16 h = (__bf16)f;
  return __builtin_bit_cast(unsigned short, h);
}

// W staging swizzle for phase 1 (b128 frags of 8 consecutive d).
static __device__ __forceinline__ int wsw_idx(int e, int d) {
  return ((((d >> 3) << 9) + (e << 3) + (d & 7)) ^ (((d >> 3) & 3) << 3));
}

__global__ __launch_bounds__(kThreads, 2) void ts_attn_fused(
    const float* __restrict__ x, const float* __restrict__ Wq_t,
    const float* __restrict__ Wk_t, const float* __restrict__ Wv_t,
    const float* __restrict__ Wq_s, const float* __restrict__ Wk_s,
    const float* __restrict__ Wv_s, const float* __restrict__ Wd_t,
    const float* __restrict__ bd_t, const float* __restrict__ Wd_s,
    const float* __restrict__ bd_s, float* __restrict__ out,
    unsigned short* __restrict__ qws) {
  extern __shared__ __align__(16) unsigned short smem[];
  unsigned short* Ksw = smem;            // 16384 us
  unsigned short* Vsw = smem + 16384;    // 16384 us
  unsigned short* slot = smem + 32768;   // 4096 us

  const int tid = threadIdx.x;
  const int wv = tid >> 6;    // wave 0..7
  const int lane = tid & 63;
  const int ln = lane & 15;   // q position within 16-tile
  const int quad = lane >> 4;
  const int e8 = ln & 7;
  const int bp = blockIdx.x;
  const int b = bp >> 1;      // batch
  const int h = bp & 1;       // q-tile half

  const float* xb = x + (size_t)b * (512 * 64);
  float* outb = out + (size_t)b * (512 * 64);
  unsigned short* qg = qws + (size_t)b * (512 * 64);  // Q bf16, slot-group order
  // (block pair shares qg but touches disjoint rows; each block reads only
  //  the rows it wrote itself -> no cross-block visibility needed)

  // Phase-2 read bases (lane-constant)
  const int kb0 = ln * 64 + ((quad ^ e8) << 3);        // K cp=0 granule
  const int kb1 = ln * 64 + (((4 + quad) ^ e8) << 3);  // K cp=1 granule
  const int vxor = (quad << 3) ^ (e8 << 3);            // V read granule XOR

  // ---- staging / compute helpers (all fully inlined) ----
  auto stageW = [&](const float* W) {
    const int d = tid >> 3;
    const int e0 = (tid & 7) * 8;
    const float4v u = *reinterpret_cast<const float4v*>(W + d * 64 + e0);
    const float4v v = *reinterpret_cast<const float4v*>(W + d * 64 + e0 + 4);
#pragma unroll
    for (int i = 0; i < 4; ++i) slot[wsw_idx(e0 + i, d)] = f2bf(u[i]);
#pragma unroll
    for (int i = 0; i < 4; ++i) slot[wsw_idx(e0 + 4 + i, d)] = f2bf(v[i]);
  };
  auto stageWd = [&](const float* W) {
    const int d = tid >> 3;
    const int e0 = (tid & 7) * 8;
    const int cp_ = d >> 5;
    const int c = d & 31;
    const int qd_ = (c >> 2) & 3;
    const int h_ = ((c >> 4) << 2) | (c & 3);
    const int gbase = cp_ * 4 + qd_;
    const float4v u = *reinterpret_cast<const float4v*>(W + d * 64 + e0);
    const float4v v = *reinterpret_cast<const float4v*>(W + d * 64 + e0 + 4);
#pragma unroll
    for (int i = 0; i < 4; ++i) {
      const int e = e0 + i;
      slot[e * 64 + ((gbase ^ (e & 7)) << 3) + h_] = f2bf(u[i]);
    }
#pragma unroll
    for (int i = 0; i < 4; ++i) {
      const int e = e0 + 4 + i;
      slot[e * 64 + ((gbase ^ (e & 7)) << 3) + h_] = f2bf(v[i]);
    }
  };
  auto loadX = [&](int grow, short8& xa0, short8& xa1) {
    const float4v u0 = *reinterpret_cast<const float4v*>(xb + grow * 64 + quad * 8);
    const float4v v0 = *reinterpret_cast<const float4v*>(xb + grow * 64 + quad * 8 + 4);
    const float4v u1 = *reinterpret_cast<const float4v*>(xb + grow * 64 + 32 + quad * 8);
    const float4v v1 = *reinterpret_cast<const float4v*>(xb + grow * 64 + 32 + quad * 8 + 4);
#pragma unroll
    for (int i = 0; i < 4; ++i) {
      xa0[i] = (short)f2bf(u0[i]);
      xa0[4 + i] = (short)f2bf(v0[i]);
      xa1[i] = (short)f2bf(u1[i]);
      xa1[4 + i] = (short)f2bf(v1[i]);
    }
  };
  auto mmW = [&](const short8& xa0, const short8& xa1, int nt) -> float4v {
    const short8 w0 = *reinterpret_cast<const short8*>(slot + wsw_idx(nt * 16 + ln, quad * 8));
    const short8 w1 = *reinterpret_cast<const short8*>(slot + wsw_idx(nt * 16 + ln, 32 + quad * 8));
    float4v acc = {0.f, 0.f, 0.f, 0.f};
    acc = MFMA16(w0, xa0, acc);
    acc = MFMA16(w1, xa1, acc);
    return acc;  // acc[r] = M[row][e = nt*16 + quad*4 + r]
  };
  auto writeQ = [&](int grow, int nt, float4v acc) {
    short4v pk;
#pragma unroll
    for (int r = 0; r < 4; ++r) pk[r] = (short)f2bf(acc[r]);
    *reinterpret_cast<short4v*>(qg + grow * 64 + (nt >> 1) * 32 + quad * 8 + (nt & 1) * 4) = pk;
  };
  auto writeK = [&](int lrow, int nt, float4v acc) {
    short4v pk;
#pragma unroll
    for (int r = 0; r < 4; ++r) pk[r] = (short)f2bf(acc[r]);
    const int gswz = ((nt >> 1) * 4 + quad) ^ (lrow & 7);
    *reinterpret_cast<short4v*>(Ksw + lrow * 64 + (gswz << 3) + (nt & 1) * 4) = pk;
  };
  auto writeV = [&](int lrow, int nt, float4v acc) {
    const int kpqL = lrow >> 5;  // 0..7 (local kp group)
    const int w5 = lrow & 31;
    const int jj = ((w5 >> 4) << 2) | (w5 & 3);
    const int qg2 = (w5 >> 2) & 3;
#pragma unroll
    for (int r = 0; r < 4; ++r) {
      const int d = nt * 16 + quad * 4 + r;
      const int gv = kpqL ^ (d & 7) ^ qg2;
      Vsw[(d << 8) + (qg2 << 6) + (gv << 3) + jj] = f2bf(acc[r]);
    }
  };

#pragma unroll 1
  for (int br = 0; br < 2; ++br) {
    const float* Wq = br ? Wq_s : Wq_t;
    const float* Wk = br ? Wk_s : Wk_t;
    const float* Wv = br ? Wv_s : Wv_t;
    const float* Wd = br ? Wd_s : Wd_t;

    // ---- just-in-time staged phase 1 (single W slot) ----
    stageW(Wq);
    __syncthreads();
#pragma unroll 1
    for (int i = 0; i < 2; ++i) {  // Q: this block's 16 q-tiles -> qws
      const int grow = (h * 16 + wv + i * 8) * 16 + ln;
      short8 xa0, xa1;
      loadX(grow, xa0, xa1);
#pragma unroll
      for (int nt = 0; nt < 4; ++nt) writeQ(grow, nt, mmW(xa0, xa1, nt));
    }
    __syncthreads();  // slot readers done before restage

    stageW(Wk);
    __syncthreads();
#pragma unroll 1
    for (int i = 0; i < 2; ++i) {  // K pos-half 0 -> Ksw
      const int lrow = (wv + i * 8) * 16 + ln;
      short8 xa0, xa1;
      loadX(lrow, xa0, xa1);
#pragma unroll
      for (int nt = 0; nt < 4; ++nt) writeK(lrow, nt, mmW(xa0, xa1, nt));
    }
    __syncthreads();

    stageW(Wv);
    __syncthreads();
#pragma unroll 1
    for (int i = 0; i < 2; ++i) {  // V pos-half 0 -> Vsw
      const int lrow = (wv + i * 8) * 16 + ln;
      short8 xa0, xa1;
      loadX(lrow, xa0, xa1);
#pragma unroll
      for (int nt = 0; nt < 4; ++nt) writeV(lrow, nt, mmW(xa0, xa1, nt));
    }
    __syncthreads();

    // ---- phase 2: dual q-tiles (A: h*16+wv, B: h*16+wv+8), online softmax
    //      across the two K/V position-halves ----
    const int qtA = h * 16 + wv;
    const int qtB = h * 16 + wv + 8;
    const unsigned short* qrowA = qg + (qtA * 16 + ln) * 64;
    const unsigned short* qrowB = qg + (qtB * 16 + ln) * 64;
    const short8 qaA = *reinterpret_cast<const short8*>(qrowA + quad * 8);
    const short8 qbA = *reinterpret_cast<const short8*>(qrowA + 32 + quad * 8);
    const short8 qaB = *reinterpret_cast<const short8*>(qrowB + quad * 8);
    const short8 qbB = *reinterpret_cast<const short8*>(qrowB + 32 + quad * 8);

    float4v oA[4], oB[4];
#pragma unroll
    for (int i = 0; i < 4; ++i) {
      oA[i] = (float4v){0.f, 0.f, 0.f, 0.f};
      oB[i] = (float4v){0.f, 0.f, 0.f, 0.f};
    }
    float mrunA = -3.0e38f, mrunB = -3.0e38f;
    float sumA = 0.f, sumB = 0.f;

#pragma unroll 1
    for (int p = 0; p < 2; ++p) {
      // sweep this half's 16 k-tiles, S-window = 4 tiles
#pragma unroll 1
      for (int ch = 0; ch < 4; ++ch) {
        float4v sA[4], sB[4];
#pragma unroll
        for (int k8 = 0; k8 < 4; ++k8) {
          const int kt = ch * 4 + k8;  // local k-tile
          const short8 k0 = *reinterpret_cast<const short8*>(Ksw + kt * 1024 + kb0);
          const short8 k1 = *reinterpret_cast<const short8*>(Ksw + kt * 1024 + kb1);
          float4v aA = {0.f, 0.f, 0.f, 0.f};
          aA = MFMA16(k0, qaA, aA);
          aA = MFMA16(k1, qbA, aA);
          sA[k8] = aA;
          float4v aB = {0.f, 0.f, 0.f, 0.f};
          aB = MFMA16(k0, qaB, aB);
          aB = MFMA16(k1, qbB, aB);
          sB[k8] = aB;
        }

        float4v m4A = sA[0], m4B = sB[0];
#pragma unroll
        for (int k8 = 1; k8 < 4; ++k8)
#pragma unroll
          for (int r = 0; r < 4; ++r) {
            m4A[r] = fmaxf(m4A[r], sA[k8][r]);
            m4B[r] = fmaxf(m4B[r], sB[k8][r]);
          }
        float cmxA = fmaxf(fmaxf(m4A[0], m4A[1]), fmaxf(m4A[2], m4A[3]));
        float cmxB = fmaxf(fmaxf(m4B[0], m4B[1]), fmaxf(m4B[2], m4B[3]));
        cmxA = fmaxf(cmxA, __shfl_xor(cmxA, 16, 64));
        cmxB = fmaxf(cmxB, __shfl_xor(cmxB, 16, 64));
        cmxA = fmaxf(cmxA, __shfl_xor(cmxA, 32, 64));
        cmxB = fmaxf(cmxB, __shfl_xor(cmxB, 32, 64));

        const float mnewA = fmaxf(mrunA, cmxA);
        const float mnewB = fmaxf(mrunB, cmxB);
        const float scaleA = __expf((mrunA - mnewA) * 0.125f);  // 0 on first chunk
        const float scaleB = __expf((mrunB - mnewB) * 0.125f);
        sumA *= scaleA;
        sumB *= scaleB;
#pragma unroll
        for (int i = 0; i < 4; ++i)
#pragma unroll
          for (int r = 0; r < 4; ++r) {
            oA[i][r] *= scaleA;
            oB[i][r] *= scaleB;
          }
        const float offsA = -mnewA * 0.125f;
        const float offsB = -mnewB * 0.125f;
        mrunA = mnewA;
        mrunB = mnewB;

#pragma unroll
        for (int kp = 0; kp < 2; ++kp) {
          float pA[8], pB[8];
#pragma unroll
          for (int hh = 0; hh < 2; ++hh) {
            const int k8 = kp * 2 + hh;
#pragma unroll
            for (int r = 0; r < 4; ++r) {
              pA[hh * 4 + r] = __expf(fmaf(sA[k8][r], 0.125f, offsA));
              pB[hh * 4 + r] = __expf(fmaf(sB[k8][r], 0.125f, offsB));
            }
          }
          sumA += ((pA[0] + pA[4]) + (pA[1] + pA[5])) + ((pA[2] + pA[6]) + (pA[3] + pA[7]));
          sumB += ((pB[0] + pB[4]) + (pB[1] + pB[5])) + ((pB[2] + pB[6]) + (pB[3] + pB[7]));
          short8 pfA, pfB;
#pragma unroll
          for (int j = 0; j < 8; ++j) {
            pfA[j] = (short)f2bf(pA[j]);
            pfB[j] = (short)f2bf(pB[j]);
          }
          const int kpg = ch * 2 + kp;  // local kp group 0..7
#pragma unroll
          for (int nto = 0; nto < 4; ++nto) {
            const int vb = (nto * 16 + ln) * 256 + quad * 64;
            const short8 vf = *reinterpret_cast<const short8*>(
                Vsw + vb + (((kpg << 3) ^ vxor)));
            oA[nto] = MFMA16(vf, pfA, oA[nto]);
            oB[nto] = MFMA16(vf, pfB, oB[nto]);
          }
        }
      }

      if (p == 0) {
        // restage K/V for position-half 1 (o/m/sum stay live in registers)
        __syncthreads();  // all waves done reading Ksw/Vsw half 0
        stageW(Wk);
        __syncthreads();
#pragma unroll 1
        for (int i = 0; i < 2; ++i) {
          const int lrow = (wv + i * 8) * 16 + ln;
          short8 xa0, xa1;
          loadX(256 + lrow, xa0, xa1);
#pragma unroll
          for (int nt = 0; nt < 4; ++nt) writeK(lrow, nt, mmW(xa0, xa1, nt));
        }
        __syncthreads();
        stageW(Wv);
        __syncthreads();
#pragma unroll 1
        for (int i = 0; i < 2; ++i) {
          const int lrow = (wv + i * 8) * 16 + ln;
          short8 xa0, xa1;
          loadX(256 + lrow, xa0, xa1);  // L2-hot re-read
#pragma unroll
          for (int nt = 0; nt < 4; ++nt) writeV(lrow, nt, mmW(xa0, xa1, nt));
        }
        __syncthreads();
      }
    }

    sumA += __shfl_xor(sumA, 16, 64);
    sumB += __shfl_xor(sumB, 16, 64);
    sumA += __shfl_xor(sumA, 32, 64);
    sumB += __shfl_xor(sumB, 32, 64);
    const float invA = 1.0f / sumA;
    const float invB = 1.0f / sumB;

    short8 of0A, of1A, of0B, of1B;
#pragma unroll
    for (int r = 0; r < 4; ++r) {
      of0A[r] = (short)f2bf(oA[0][r] * invA);
      of0A[4 + r] = (short)f2bf(oA[1][r] * invA);
      of1A[r] = (short)f2bf(oA[2][r] * invA);
      of1A[4 + r] = (short)f2bf(oA[3][r] * invA);
      of0B[r] = (short)f2bf(oB[0][r] * invB);
      of0B[4 + r] = (short)f2bf(oB[1][r] * invB);
      of1B[r] = (short)f2bf(oB[2][r] * invB);
      of1B[4 + r] = (short)f2bf(oB[3][r] * invB);
    }

    // Wd -> slot (Wd2 layout). slot's last readers (V half-1 compute) were
    // synced; the sweep reads only Ksw/Vsw, so writing slot here is safe.
    stageWd(Wd);
    __syncthreads();

    // dense: Z^T = Wd^T @ O^T; Wd frags shared A/B; float4 epilogue
#pragma unroll
    for (int nt = 0; nt < 4; ++nt) {
      const int ebase = (nt * 16 + ln) * 64;
      const short8 w0 = *reinterpret_cast<const short8*>(
          slot + ebase + ((quad ^ e8) << 3));
      const short8 w1 = *reinterpret_cast<const short8*>(
          slot + ebase + (((4 + quad) ^ e8) << 3));
      float4v accA = {0.f, 0.f, 0.f, 0.f};
      accA = MFMA16(w0, of0A, accA);
      accA = MFMA16(w1, of1A, accA);
      float4v accB = {0.f, 0.f, 0.f, 0.f};
      accB = MFMA16(w0, of0B, accB);
      accB = MFMA16(w1, of1B, accB);
      const int e0 = nt * 16 + quad * 4;
#pragma unroll
      for (int t = 0; t < 2; ++t) {
        const int row = (t == 0 ? qtA : qtB) * 16 + ln;
        const float4v acc = t == 0 ? accA : accB;
        float4v* op = reinterpret_cast<float4v*>(outb + row * 64 + e0);
        if (br == 0) {
          *op = acc;  // park temporal branch (sans bias)
        } else {
          const float4v bt = *reinterpret_cast<const float4v*>(bd_t + e0);
          const float4v bs = *reinterpret_cast<const float4v*>(bd_s + e0);
          const float4v parked = *op;
          const float4v xv = *reinterpret_cast<const float4v*>(xb + row * 64 + e0);
          float4v res;
#pragma unroll
          for (int r = 0; r < 4; ++r) {
            const float z = parked[r] + acc[r] + bt[r] + bs[r];
            const float gate = 1.0f / (1.0f + __expf(-z));
            res[r] = xv[r] * gate;
          }
          *op = res;
        }
      }
    }
    __syncthreads();  // protect slot/Ksw/Vsw before next branch restages
  }
}

extern "C" void kernel_launch(void* const* d_in, const int* in_sizes, int n_in,
                              void* d_out, int out_size, void* d_ws, size_t ws_size,
                              hipStream_t stream) {
  const float* x = (const float*)d_in[0];
  const float* Wq_t = (const float*)d_in[1];
  const float* Wk_t = (const float*)d_in[2];
  const float* Wv_t = (const float*)d_in[3];
  const float* Wq_s = (const float*)d_in[4];
  const float* Wk_s = (const float*)d_in[5];
  const float* Wv_s = (const float*)d_in[6];
  const float* Wd_t = (const float*)d_in[7];
  const float* bd_t = (const float*)d_in[8];
  const float* Wd_s = (const float*)d_in[9];
  const float* bd_s = (const float*)d_in[10];
  float* out = (float*)d_out;
  unsigned short* qws = (unsigned short*)d_ws;  // 256*512*64*2 = 16 MiB

  hipFuncSetAttribute(reinterpret_cast<const void*>(ts_attn_fused),
                      hipFuncAttributeMaxDynamicSharedMemorySize, LDS_TOTAL_BYTES);
  ts_attn_fused<<<dim3(512), dim3(kThreads), LDS_TOTAL_BYTES, stream>>>(
      x, Wq_t, Wk_t, Wv_t, Wq_s, Wk_s, Wv_s, Wd_t, bd_t, Wd_s, bd_s, out, qws);
}